// Round 18
// baseline (63.442 us; speedup 1.0000x reference)
//
#include <hip/hip_runtime.h>
#include <hip/hip_bf16.h>
#include <stdint.h>

typedef short bf16x8 __attribute__((ext_vector_type(8)));
typedef float f32x4 __attribute__((ext_vector_type(4)));

#define D  512
#define NB 4096
#define NT 8192

__device__ __forceinline__ unsigned short f2bf(float f) {
    __hip_bfloat16 h = __float2bfloat16(f);
    return *reinterpret_cast<unsigned short*>(&h);
}

// Fused fp32->bf16 convert + row squared-norm for BOTH inputs; x rows also
// write the fp32 passthrough (output 0). One wave per row. HBM-floor bound.
__global__ __launch_bounds__(256) void prep_kernel(
    const float* __restrict__ x, const float* __restrict__ y,
    unsigned short* __restrict__ xb, unsigned short* __restrict__ yb,
    float* __restrict__ x2, float* __restrict__ y2, float* __restrict__ copy)
{
    const int grow = blockIdx.x * 4 + (threadIdx.x >> 6);
    const int lane = threadIdx.x & 63;
    const bool isX = grow < NB;
    const int row  = isX ? grow : grow - NB;
    const float* src = isX ? x : y;
    unsigned short* dst = isX ? xb : yb;
    float* norms = isX ? x2 : y2;

    const float4* rp = reinterpret_cast<const float4*>(src + (size_t)row * D);
    float4 v0 = rp[lane * 2];
    float4 v1 = rp[lane * 2 + 1];
    if (isX) {
        float4* cp = reinterpret_cast<float4*>(copy + (size_t)row * D);
        cp[lane * 2]     = v0;
        cp[lane * 2 + 1] = v1;
    }
    float s = v0.x*v0.x + v0.y*v0.y + v0.z*v0.z + v0.w*v0.w
            + v1.x*v1.x + v1.y*v1.y + v1.z*v1.z + v1.w*v1.w;
    union { unsigned short h[8]; int4 v; } u;
    u.h[0] = f2bf(v0.x); u.h[1] = f2bf(v0.y); u.h[2] = f2bf(v0.z); u.h[3] = f2bf(v0.w);
    u.h[4] = f2bf(v1.x); u.h[5] = f2bf(v1.y); u.h[6] = f2bf(v1.z); u.h[7] = f2bf(v1.w);
    reinterpret_cast<int4*>(dst + (size_t)row * D)[lane] = u.v;
    #pragma unroll
    for (int off = 32; off > 0; off >>= 1) s += __shfl_xor(s, off);
    if (lane == 0) norms[row] = s;
}

// R17 (128x128 tile, 4 waves 2x2, 4 blocks/CU, 57.95 µs) with ONE
// structural change: BK 64 -> 32 with LDS DOUBLE-BUFFER in the same
// 32 KiB (2 x {A[128][32] 8KB + B[128][32] 8KB}) -> pipelining AND max
// occupancy together (untested combination; pipelining alone was neutral
// at 2 blocks/CU, drain-per-step at 4 blocks/CU is the current best).
// Per kt: stage kt+1 into buf^1 (4 loads) -> vmcnt(4) retires kt's loads
// (latency covered by previous iter's compute) -> barrier -> 8 ds_read +
// 16 MFMA (K=32) -> lgkm(0) -> barrier (protects buf from kt+2's stage).
// Swizzle (rule #21): source chunk g=(t&3)^((t>>2)&3); read-side constant
// (lane>>4)^(lane&3); per-instruction spread = uniform 8 lanes per 4-bank
// group = the b128 8-beat floor (conflict-free).
__global__ __launch_bounds__(256, 4) void gemm_sim_kernel(
    const unsigned short* __restrict__ X, const unsigned short* __restrict__ Y,
    const float* __restrict__ x2, const float* __restrict__ y2,
    float* __restrict__ out)
{
    __shared__ alignas(16) unsigned short lds[16384];   // 32 KiB: 2 bufs x 8192 ush

    const int t    = threadIdx.x;
    const int lane = t & 63;
    const int w    = t >> 6;          // 0..3
    const int wr   = w >> 1;          // 0..1 (row half, 64 rows)
    const int wc   = w & 1;           // 0..1 (col half, 64 cols)

    // 2048 blocks; per XCD 16 rowTiles x 16 colTiles (A 2MB + B 2MB L2-fit).
    const int bid = blockIdx.x;
    const int xcd = bid & 7;
    const int idx = bid >> 3;                          // 0..255
    const int rowBase = ((xcd & 1) * 16 + (idx & 15)) * 128;
    const int colBase = ((xcd >> 1) * 16 + (idx >> 4)) * 128;

    // Staging: thread t writes 16 B at LDS ushort off t*8 (+L*2048 = +64
    // rows), i.e. row (t>>2)+64L, stored chunk t&3. Source pre-swizzle:
    // global chunk g = (t&3) ^ ((t>>2)&3)  (row&3 invariant under +64).
    const int g = ((t & 3) ^ ((t >> 2) & 3)) * 8;
    const unsigned short* gA = X + (size_t)(rowBase + (t >> 2)) * D + g;
    const unsigned short* gB = Y + (size_t)(colBase + (t >> 2)) * D + g;

    // Read side: global chunk lane>>4, stored at ^(row&3) -> per-lane const.
    const int sc = ((lane >> 4) ^ (lane & 3)) * 8;
    const int aoff = (wr * 64 + (lane & 15)) * 32 + sc;          // + buf + m*512
    const int boff = 4096 + (wc * 64 + (lane & 15)) * 32 + sc;   // + buf + n*512

    f32x4 acc[4][4] = {};

#define STAGE(KT, BUF) do { \
    _Pragma("unroll") \
    for (int L = 0; L < 2; ++L) { \
        __builtin_amdgcn_global_load_lds( \
            (const __attribute__((address_space(1))) void*)(gA + (size_t)L * 64 * D + (KT) * 32), \
            (__attribute__((address_space(3))) void*)(lds + (BUF) * 8192 + t * 8 + L * 2048), 16, 0, 0); \
        __builtin_amdgcn_global_load_lds( \
            (const __attribute__((address_space(1))) void*)(gB + (size_t)L * 64 * D + (KT) * 32), \
            (__attribute__((address_space(3))) void*)(lds + (BUF) * 8192 + 4096 + t * 8 + L * 2048), 16, 0, 0); \
    } \
} while (0)

    // Prologue: stage kt0 into buf0.
    STAGE(0, 0);

    // 16 K-steps (K=512 / BK=32), double-buffered.
#pragma unroll
    for (int kt = 0; kt < 16; ++kt) {
        if (kt + 1 < 16) {
            STAGE(kt + 1, (kt + 1) & 1);
            asm volatile("s_waitcnt vmcnt(4)" ::: "memory");  // kt's 4 landed
        } else {
            asm volatile("s_waitcnt vmcnt(0)" ::: "memory");
        }
        __builtin_amdgcn_s_barrier();
        const int bufo = (kt & 1) * 8192;
        bf16x8 a[4], b[4];
        #pragma unroll
        for (int m = 0; m < 4; ++m)
            a[m] = *(const bf16x8*)(lds + bufo + aoff + m * 512);
        #pragma unroll
        for (int n = 0; n < 4; ++n)
            b[n] = *(const bf16x8*)(lds + bufo + boff + n * 512);
        __builtin_amdgcn_s_setprio(1);
        #pragma unroll
        for (int m = 0; m < 4; ++m)
            #pragma unroll
            for (int n = 0; n < 4; ++n)
                acc[m][n] = __builtin_amdgcn_mfma_f32_16x16x32_bf16(
                    a[m], b[n], acc[m][n], 0, 0, 0);
        __builtin_amdgcn_s_setprio(0);
        asm volatile("s_waitcnt lgkmcnt(0)" ::: "memory");
        if (kt < 15) __builtin_amdgcn_s_barrier();   // buf safe for kt+2 stage
    }
#undef STAGE

    // Epilogue: C/D layout col = lane&15, row = (lane>>4)*4 + reg.
    const int col0 = colBase + wc * 64 + (lane & 15);
    const int row0 = rowBase + wr * 64 + ((lane >> 4) << 2);
    #pragma unroll
    for (int m = 0; m < 4; ++m) {
        #pragma unroll
        for (int q = 0; q < 4; ++q) {
            const int grow = row0 + m * 16 + q;
            const float xn = x2[grow];
            float* orow = out + (size_t)grow * NT;
            #pragma unroll
            for (int n = 0; n < 4; ++n) {
                const int gcol = col0 + n * 16;
                float sq = fmaxf(xn + y2[gcol] - 2.0f * acc[m][n][q], 0.0f);
                orow[gcol] = fminf(rsqrtf(sq), 1.0e6f);  // rsqrt(0)=inf -> clipped
            }
        }
    }
}

extern "C" void kernel_launch(void* const* d_in, const int* in_sizes, int n_in,
                              void* d_out, int out_size, void* d_ws, size_t ws_size,
                              hipStream_t stream)
{
    const float* x = (const float*)d_in[0];
    const float* y = (const float*)d_in[1];
    float* out = (float*)d_out;
    char* ws = (char*)d_ws;

    unsigned short* xb = (unsigned short*)ws;                 // 4 MB
    unsigned short* yb = (unsigned short*)(ws + (4u << 20));  // 8 MB
    float* x2 = (float*)(ws + (12u << 20));                   // 16 KB
    float* y2 = (float*)(ws + (12u << 20) + 4 * NB);          // 32 KB

    prep_kernel<<<(NB + NT) / 4, 256, 0, stream>>>(x, y, xb, yb, x2, y2, out);
    gemm_sim_kernel<<<2048, 256, 0, stream>>>(xb, yb, x2, y2, out + (size_t)NB * D);
}